// Round 2
// baseline (516.003 us; speedup 1.0000x reference)
//
#include <hip/hip_runtime.h>

#define IMG 256
#define FBIG 1e10f
#define EPSA 1e-8f
#define NSLICE 8

// Per-face precomputed record, 64B:
// a: x1,y1, y2-y1, x2-x1   (edge0: w0 numerator)
// b: x2,y2, y0-y2, x0-x2   (edge1)
// c: x0,y0, y1-y0, x1-x0   (edge2)
// d: z0,z1,z2, area(=denom)
struct __align__(16) FRec { float4 a, b, c, d; };

__global__ __launch_bounds__(256) void precompute_kernel(
    const float* __restrict__ verts, const int* __restrict__ faces,
    FRec* __restrict__ rec, int* __restrict__ fids,
    unsigned int* __restrict__ cnt, int V, int F)
{
#pragma clang fp contract(off)
    const int f = blockIdx.x * 256 + threadIdx.x;
    const int b = blockIdx.y;
    if (f >= F) return;
    const float* vb = verts + (size_t)b * V * 3;
    const int i0 = faces[3*f+0], i1 = faces[3*f+1], i2 = faces[3*f+2];
    const float x0 = -vb[3*i0+0], y0 = -vb[3*i0+1], z0 = vb[3*i0+2];
    const float x1 = -vb[3*i1+0], y1 = -vb[3*i1+1], z1 = vb[3*i1+2];
    const float x2 = -vb[3*i2+0], y2 = -vb[3*i2+1], z2 = vb[3*i2+2];
    const float area = (x1 - x0) * (y2 - y0) - (y1 - y0) * (x2 - x0);
    const float zmax = fmaxf(fmaxf(z0, z1), z2);
    if (area > EPSA && zmax >= 0.0f) {
        const unsigned int slot = atomicAdd(&cnt[b], 1u);
        FRec r;
        r.a = make_float4(x1, y1, y2 - y1, x2 - x1);
        r.b = make_float4(x2, y2, y0 - y2, x0 - x2);
        r.c = make_float4(x0, y0, y1 - y0, x1 - x0);
        r.d = make_float4(z0, z1, z2, area);
        rec[(size_t)b * F + slot]  = r;
        fids[(size_t)b * F + slot] = f;
    }
}

__global__ __launch_bounds__(256, 8) void raster_kernel(
    const FRec* __restrict__ rec, const int* __restrict__ fids,
    const unsigned int* __restrict__ cnt,
    unsigned long long* __restrict__ zpix, int F)
{
#pragma clang fp contract(off)
    const int b    = blockIdx.y;
    const int tile = blockIdx.x;           // 0..255
    const int ti = tile >> 4, tj = tile & 15;
    const int tid = threadIdx.x;
    const int row = ti * 16 + (tid >> 4);
    const int col = tj * 16 + (tid & 15);
    const float px = 1.0f - (2.0f * (float)col + 1.0f) / 256.0f;
    const float py = 1.0f - (2.0f * (float)row + 1.0f) / 256.0f;

    int n = (int)cnt[b];
    n = __builtin_amdgcn_readfirstlane(n);          // force SGPR -> scalar record loads
    const int per = (n + NSLICE - 1) / NSLICE;
    const int f0 = blockIdx.z * per;
    const int f1 = min(f0 + per, n);

    const FRec* rb = rec  + (size_t)b * F;
    const int*  fb = fids + (size_t)b * F;

    unsigned long long best = ~0ULL;
    for (int i = f0; i < f1; ++i) {
        const FRec r  = rb[i];
        const int fid = fb[i];
        const float e0 = (px - r.a.x) * r.a.z - (py - r.a.y) * r.a.w;
        const float e1 = (px - r.b.x) * r.b.z - (py - r.b.y) * r.b.w;
        const float e2 = (px - r.c.x) * r.c.z - (py - r.c.y) * r.c.w;
        if (e0 >= 0.0f && e1 >= 0.0f && e2 >= 0.0f) {
            const float w0 = e0 / r.d.w;
            const float w1 = e1 / r.d.w;
            const float w2 = e2 / r.d.w;
            const float pz = (w0 * r.d.x + w1 * r.d.y) + w2 * r.d.z;
            if (pz >= 0.0f && pz < FBIG) {
                const unsigned int zb = __float_as_uint(pz + 0.0f);  // -0.0 -> +0.0
                const unsigned long long cand =
                    ((unsigned long long)zb << 32) | (unsigned int)fid;
                best = cand < best ? cand : best;
            }
        }
    }
    if (best != ~0ULL) {
        const int pix = (b * IMG + row) * IMG + col;
        atomicMin(&zpix[pix], best);
    }
}

__global__ __launch_bounds__(256) void resolve_kernel(
    const float* __restrict__ verts, const int* __restrict__ faces,
    const unsigned long long* __restrict__ zpix,
    float* __restrict__ out, int B, int V, int F)
{
#pragma clang fp contract(off)
    const int idx = blockIdx.x * 256 + threadIdx.x;
    if (idx >= B * IMG * IMG) return;
    const int b   = idx / (IMG * IMG);
    const int p   = idx - b * (IMG * IMG);
    const int row = p >> 8, col = p & 255;

    const unsigned long long v = zpix[idx];
    float p2f = -1.0f, o0 = -1.0f, o1 = -1.0f, o2 = -1.0f;
    if (v != ~0ULL) {
        const int fid = (int)(v & 0xFFFFFFFFu);
        const float* vb = verts + (size_t)b * V * 3;
        const int i0 = faces[3*fid+0], i1 = faces[3*fid+1], i2 = faces[3*fid+2];
        const float x0 = -vb[3*i0+0], y0 = -vb[3*i0+1];
        const float x1 = -vb[3*i1+0], y1 = -vb[3*i1+1];
        const float x2 = -vb[3*i2+0], y2 = -vb[3*i2+1];
        const float area = (x1 - x0) * (y2 - y0) - (y1 - y0) * (x2 - x0);
        const float px = 1.0f - (2.0f * (float)col + 1.0f) / 256.0f;
        const float py = 1.0f - (2.0f * (float)row + 1.0f) / 256.0f;
        const float e0 = (px - x1) * (y2 - y1) - (py - y1) * (x2 - x1);
        const float e1 = (px - x2) * (y0 - y2) - (py - y2) * (x0 - x2);
        const float e2 = (px - x0) * (y1 - y0) - (py - y0) * (x1 - x0);
        o0 = e0 / area; o1 = e1 / area; o2 = e2 / area;
        p2f = (float)(fid + b * F);
    }
    out[idx] = p2f;
    const size_t boff = (size_t)B * IMG * IMG + (size_t)idx * 3;
    out[boff + 0] = o0; out[boff + 1] = o1; out[boff + 2] = o2;
}

extern "C" void kernel_launch(void* const* d_in, const int* in_sizes, int n_in,
                              void* d_out, int out_size, void* d_ws, size_t ws_size,
                              hipStream_t stream) {
    const float* vertices = (const float*)d_in[0];
    const int*   faces    = (const int*)d_in[1];
    float* out = (float*)d_out;

    const int F = in_sizes[1] / 3;
    const int B = 2;
    const int V = in_sizes[0] / (3 * B);

    // ws layout
    char* w = (char*)d_ws;
    unsigned int* cnt = (unsigned int*)w;                       // B counters
    FRec* rec = (FRec*)(w + 256);
    int*  fids = (int*)(w + 256 + (size_t)B * F * sizeof(FRec));
    size_t zoff = 256 + (size_t)B * F * (sizeof(FRec) + 4);
    zoff = (zoff + 255) & ~(size_t)255;
    unsigned long long* zpix = (unsigned long long*)(w + zoff);
    const size_t npix = (size_t)B * IMG * IMG;

    hipMemsetAsync(cnt, 0, B * sizeof(unsigned int), stream);
    hipMemsetAsync(zpix, 0xFF, npix * 8, stream);

    dim3 gpre((F + 255) / 256, B);
    precompute_kernel<<<gpre, 256, 0, stream>>>(vertices, faces, rec, fids, cnt, V, F);

    dim3 gras(256, B, NSLICE);
    raster_kernel<<<gras, 256, 0, stream>>>(rec, fids, cnt, zpix, F);

    dim3 gres((unsigned)((npix + 255) / 256));
    resolve_kernel<<<gres, 256, 0, stream>>>(vertices, faces, zpix, out, B, V, F);
}

// Round 3
// 201.723 us; speedup vs baseline: 2.5580x; 2.5580x over previous
//
#include <hip/hip_runtime.h>

#define IMG 256
#define FBIG 1e10f
#define EPSA 1e-8f
#define BPAD 1e-4f
#define NSLICE 8
#define CHUNK 256

// Per-face precomputed record, 64B:
// a: x1,y1, y2-y1, x2-x1   (edge0: w0 numerator)
// b: x2,y2, y0-y2, x0-x2   (edge1)
// c: x0,y0, y1-y0, x1-x0   (edge2)
// d: z0,z1,z2, area(=denom)
struct __align__(16) FRec { float4 a, b, c, d; };

__global__ __launch_bounds__(256) void precompute_kernel(
    const float* __restrict__ verts, const int* __restrict__ faces,
    FRec* __restrict__ rec, float4* __restrict__ bboxes, int* __restrict__ fids,
    unsigned int* __restrict__ cnt, int V, int F)
{
#pragma clang fp contract(off)
    const int f = blockIdx.x * 256 + threadIdx.x;
    const int b = blockIdx.y;
    if (f >= F) return;
    const float* vb = verts + (size_t)b * V * 3;
    const int i0 = faces[3*f+0], i1 = faces[3*f+1], i2 = faces[3*f+2];
    const float x0 = -vb[3*i0+0], y0 = -vb[3*i0+1], z0 = vb[3*i0+2];
    const float x1 = -vb[3*i1+0], y1 = -vb[3*i1+1], z1 = vb[3*i1+2];
    const float x2 = -vb[3*i2+0], y2 = -vb[3*i2+1], z2 = vb[3*i2+2];
    const float area = (x1 - x0) * (y2 - y0) - (y1 - y0) * (x2 - x0);
    const float zmax = fmaxf(fmaxf(z0, z1), z2);
    if (area > EPSA && zmax >= 0.0f) {
        const unsigned int slot = atomicAdd(&cnt[b], 1u);
        FRec r;
        r.a = make_float4(x1, y1, y2 - y1, x2 - x1);
        r.b = make_float4(x2, y2, y0 - y2, x0 - x2);
        r.c = make_float4(x0, y0, y1 - y0, x1 - x0);
        r.d = make_float4(z0, z1, z2, area);
        rec[(size_t)b * F + slot]  = r;
        fids[(size_t)b * F + slot] = f;
        bboxes[(size_t)b * F + slot] = make_float4(
            fminf(fminf(x0,x1),x2) - BPAD, fmaxf(fmaxf(x0,x1),x2) + BPAD,
            fminf(fminf(y0,y1),y2) - BPAD, fmaxf(fmaxf(y0,y1),y2) + BPAD);
    }
}

__global__ __launch_bounds__(256) void raster_kernel(
    const FRec* __restrict__ rec, const float4* __restrict__ bboxes,
    const int* __restrict__ fids, const unsigned int* __restrict__ cnt,
    unsigned long long* __restrict__ zpix, int F)
{
#pragma clang fp contract(off)
    __shared__ float s_rec[CHUNK][17];     // 16 used, stride 17 (gcd(17,32)=1)
    __shared__ float s_bb[4][CHUNK];       // transposed: stride-1 reads
    __shared__ int   s_fid[CHUNK];

    const int b     = blockIdx.y;
    const int slice = blockIdx.z;
    const int tile  = blockIdx.x;          // 0..255
    const int ti = tile >> 4, tj = tile & 15;
    const int tid  = threadIdx.x;
    const int wave = tid >> 6;
    const int lane = tid & 63;

    const int row = ti * 16 + wave * 4 + (lane >> 4);
    const int col = tj * 16 + (lane & 15);
    const float px = 1.0f - (2.0f * (float)col + 1.0f) / 256.0f;
    const float py = 1.0f - (2.0f * (float)row + 1.0f) / 256.0f;

    // wave-uniform footprint ranges (px,py decrease with pixel index)
    const float px_hi = 1.0f - (2.0f * (float)(tj * 16) + 1.0f) / 256.0f;
    const float px_lo = 1.0f - (2.0f * (float)(tj * 16 + 15) + 1.0f) / 256.0f;
    const int   r0    = ti * 16 + wave * 4;
    const float py_hi = 1.0f - (2.0f * (float)r0 + 1.0f) / 256.0f;
    const float py_lo = 1.0f - (2.0f * (float)(r0 + 3) + 1.0f) / 256.0f;

    const int n   = (int)cnt[b];
    const int nch = (n + CHUNK - 1) / CHUNK;

    const FRec*   rb = rec    + (size_t)b * F;
    const float4* bx = bboxes + (size_t)b * F;
    const int*    fb = fids   + (size_t)b * F;

    unsigned long long best = ~0ULL;

    for (int c = slice; c < nch; c += NSLICE) {
        __syncthreads();
        {
            const int f = c * CHUNK + tid;
            if (f < n) {
                const FRec r = rb[f];
                const float4 bb = bx[f];
                float* sr = s_rec[tid];
                sr[0]=r.a.x;  sr[1]=r.a.y;  sr[2]=r.a.z;  sr[3]=r.a.w;
                sr[4]=r.b.x;  sr[5]=r.b.y;  sr[6]=r.b.z;  sr[7]=r.b.w;
                sr[8]=r.c.x;  sr[9]=r.c.y;  sr[10]=r.c.z; sr[11]=r.c.w;
                sr[12]=r.d.x; sr[13]=r.d.y; sr[14]=r.d.z; sr[15]=r.d.w;
                s_fid[tid] = fb[f];
                s_bb[0][tid]=bb.x; s_bb[1][tid]=bb.y; s_bb[2][tid]=bb.z; s_bb[3][tid]=bb.w;
            } else {
                s_bb[0][tid]= 4e9f; s_bb[1][tid]=-4e9f;
                s_bb[2][tid]= 4e9f; s_bb[3][tid]=-4e9f;
            }
        }
        __syncthreads();

        for (int g = 0; g < CHUNK / 64; ++g) {
            const int fl = g * 64 + lane;
            const bool ov = (s_bb[0][fl] <= px_hi) && (s_bb[1][fl] >= px_lo) &&
                            (s_bb[2][fl] <= py_hi) && (s_bb[3][fl] >= py_lo);
            unsigned long long mask = __ballot(ov);
            while (mask) {
                const int bit = __builtin_ctzll(mask);
                mask &= mask - 1;
                const int idx = g * 64 + bit;
                const float* r = s_rec[idx];        // wave-uniform -> broadcast
                const float e0 = (px - r[0]) * r[2]  - (py - r[1]) * r[3];
                const float e1 = (px - r[4]) * r[6]  - (py - r[5]) * r[7];
                const float e2 = (px - r[8]) * r[10] - (py - r[9]) * r[11];
                if (e0 >= 0.0f && e1 >= 0.0f && e2 >= 0.0f) {
                    const float denom = r[15];
                    const float w0 = e0 / denom;
                    const float w1 = e1 / denom;
                    const float w2 = e2 / denom;
                    const float pz = (w0 * r[12] + w1 * r[13]) + w2 * r[14];
                    if (pz >= 0.0f && pz < FBIG) {
                        const unsigned int zb = __float_as_uint(pz + 0.0f);  // -0 -> +0
                        const unsigned long long cand =
                            ((unsigned long long)zb << 32) | (unsigned int)s_fid[idx];
                        best = cand < best ? cand : best;
                    }
                }
            }
        }
    }

    if (best != ~0ULL) {
        const int pix = (b * IMG + row) * IMG + col;
        atomicMin(&zpix[pix], best);
    }
}

__global__ __launch_bounds__(256) void resolve_kernel(
    const float* __restrict__ verts, const int* __restrict__ faces,
    const unsigned long long* __restrict__ zpix,
    float* __restrict__ out, int B, int V, int F)
{
#pragma clang fp contract(off)
    const int idx = blockIdx.x * 256 + threadIdx.x;
    if (idx >= B * IMG * IMG) return;
    const int b   = idx / (IMG * IMG);
    const int p   = idx - b * (IMG * IMG);
    const int row = p >> 8, col = p & 255;

    const unsigned long long v = zpix[idx];
    float p2f = -1.0f, o0 = -1.0f, o1 = -1.0f, o2 = -1.0f;
    if (v != ~0ULL) {
        const int fid = (int)(v & 0xFFFFFFFFu);
        const float* vb = verts + (size_t)b * V * 3;
        const int i0 = faces[3*fid+0], i1 = faces[3*fid+1], i2 = faces[3*fid+2];
        const float x0 = -vb[3*i0+0], y0 = -vb[3*i0+1];
        const float x1 = -vb[3*i1+0], y1 = -vb[3*i1+1];
        const float x2 = -vb[3*i2+0], y2 = -vb[3*i2+1];
        const float area = (x1 - x0) * (y2 - y0) - (y1 - y0) * (x2 - x0);
        const float px = 1.0f - (2.0f * (float)col + 1.0f) / 256.0f;
        const float py = 1.0f - (2.0f * (float)row + 1.0f) / 256.0f;
        const float e0 = (px - x1) * (y2 - y1) - (py - y1) * (x2 - x1);
        const float e1 = (px - x2) * (y0 - y2) - (py - y2) * (x0 - x2);
        const float e2 = (px - x0) * (y1 - y0) - (py - y0) * (x1 - x0);
        o0 = e0 / area; o1 = e1 / area; o2 = e2 / area;
        p2f = (float)(fid + b * F);
    }
    out[idx] = p2f;
    const size_t boff = (size_t)B * IMG * IMG + (size_t)idx * 3;
    out[boff + 0] = o0; out[boff + 1] = o1; out[boff + 2] = o2;
}

extern "C" void kernel_launch(void* const* d_in, const int* in_sizes, int n_in,
                              void* d_out, int out_size, void* d_ws, size_t ws_size,
                              hipStream_t stream) {
    const float* vertices = (const float*)d_in[0];
    const int*   faces    = (const int*)d_in[1];
    float* out = (float*)d_out;

    const int F = in_sizes[1] / 3;
    const int B = 2;
    const int V = in_sizes[0] / (3 * B);

    // ws layout
    char* w = (char*)d_ws;
    unsigned int* cnt = (unsigned int*)w;                       // B counters
    size_t off = 256;
    FRec* rec = (FRec*)(w + off);          off += (size_t)B * F * sizeof(FRec);
    float4* bboxes = (float4*)(w + off);   off += (size_t)B * F * sizeof(float4);
    int* fids = (int*)(w + off);           off += (size_t)B * F * sizeof(int);
    off = (off + 255) & ~(size_t)255;
    unsigned long long* zpix = (unsigned long long*)(w + off);
    const size_t npix = (size_t)B * IMG * IMG;

    hipMemsetAsync(cnt, 0, B * sizeof(unsigned int), stream);
    hipMemsetAsync(zpix, 0xFF, npix * 8, stream);

    dim3 gpre((F + 255) / 256, B);
    precompute_kernel<<<gpre, 256, 0, stream>>>(vertices, faces, rec, bboxes, fids, cnt, V, F);

    dim3 gras(256, B, NSLICE);
    raster_kernel<<<gras, 256, 0, stream>>>(rec, bboxes, fids, cnt, zpix, F);

    dim3 gres((unsigned)((npix + 255) / 256));
    resolve_kernel<<<gres, 256, 0, stream>>>(vertices, faces, zpix, out, B, V, F);
}